// Round 10
// baseline (464.195 us; speedup 1.0000x reference)
//
#include <hip/hip_runtime.h>
#include <math.h>

#define HIDDEN  512
#define INPUT   8
#define NUM_MIX 2
#define BATCH   64
#define SEQ     2048
#define DD      12
#define KOUT    10
#define TTILE   16
#define NTILES  (SEQ/TTILE)

// h-state kept pre-scaled by 2*log2(e): tanh(h) = 1 - 2*rcp(exp2(h_s)+1)
// dot fold: sum_j n_j*tanh_j = sum_j n_j + sum_j (-2 n_j) * r_j
#define SCALE_F 2.8853900817779268
#define AB_F    0.09765625f   /* alpha*BASE_SCALE/HIDDEN = 50/512 */

typedef float v2f __attribute__((ext_vector_type(2)));
typedef float f4v __attribute__((ext_vector_type(4)));

__device__ __forceinline__ v2f pk_fma(v2f a, v2f b, v2f c) {
    return __builtin_elementwise_fma(a, b, c);
}

template<int CTRL>
__device__ __forceinline__ float dpp_add(float x) {
    int y = __builtin_amdgcn_update_dpp(0, __float_as_int(x), CTRL, 0xF, 0xF, true);
    return x + __int_as_float(y);
}
__device__ __forceinline__ float wave_allsum(float x) {
    x = dpp_add<0x111>(x);   // row_shr:1
    x = dpp_add<0x112>(x);   // row_shr:2
    x = dpp_add<0x114>(x);   // row_shr:4
    x = dpp_add<0x118>(x);   // row_shr:8
    x = dpp_add<0x142>(x);   // row_bcast:15
    x = dpp_add<0x143>(x);   // row_bcast:31
    return __int_as_float(__builtin_amdgcn_readlane(__float_as_int(x), 63));
}

__global__ __launch_bounds__(256) void fsm_rnn_kernel(
    const float* __restrict__ x,          // (B, SEQ, INPUT)
    const float* __restrict__ means,      // (NUM_MIX, DD)
    const float* __restrict__ scale_tril, // (NUM_MIX, DD, DD)
    const float* __restrict__ mixw,       // (NUM_MIX,)
    const float* __restrict__ seeds,      // (4, HIDDEN, DD)
    const int*   __restrict__ cur_seeds,  // (B,)
    float*       __restrict__ out)        // (B, SEQ, KOUT)
{
    // IxP pair-layout: [dbuf][tt][q][lane][pr] holds unit h = lane + 64*(2q+pr)
    __shared__ __align__(16) float IxP[2][TTILE][4][64][2];  // 64KB
    __shared__ __align__(16) float xsB[2][TTILE*INPUT];      // 1KB raw x tiles
    __shared__ __align__(16) float IvL[HIDDEN][INPUT];       // 16KB alpha*I (scaled)
    __shared__ float PM0[HIDDEN], PM1[HIDDEN], N0[HIDDEN], N1[HIDDEN]; // 8KB
    __shared__ __align__(8) float vr2[2][TTILE][64][2];      // 16KB per-lane v copies
    __shared__ double Leff[DD*DD];
    __shared__ double meansw[DD];

    const int tid  = threadIdx.x;
    const int lane = tid & 63;
    const int wid  = tid >> 6;
    const int b    = blockIdx.x;
    const int s    = cur_seeds[b];
    const float* xb = x + (size_t)b * SEQ * INPUT;
    float* outb = out + (size_t)b * SEQ * KOUT;

    // ---- mixture weights ----
    double w0 = fmax((double)mixw[0], 1e-6);
    double w1 = fmax((double)mixw[1], 1e-6);
    double wsum = w0 + w1; w0 /= wsum; w1 /= wsum;

    // ---- weighted clamped-tril L, weighted means ----
    if (tid < DD*DD) {
        int d = tid / DD, e = tid % DD;
        double acc = 0.0;
        #pragma unroll
        for (int i = 0; i < NUM_MIX; ++i) {
            float v = scale_tril[i*DD*DD + d*DD + e];
            float c = (d > e) ? v : (d == e ? fabsf(v - 1e-12f) + 1e-12f : 0.0f);
            acc += (i == 0 ? w0 : w1) * (double)c;
        }
        Leff[tid] = acc;
    }
    if (tid < DD)
        meansw[tid] = w0 * (double)means[tid] + w1 * (double)means[DD + tid];
    if (tid < 2*TTILE*INPUT)
        ((float*)xsB)[tid] = xb[tid];          // stage x tiles 0,1
    __syncthreads();

    // ---- per-h params (double), stored pre-scaled ----
    #pragma unroll
    for (int rr = 0; rr < 2; ++rr) {
        int h = tid + rr*256;
        const float* sh = &seeds[(s*HIDDEN + h)*DD];
        double comb[DD];
        #pragma unroll
        for (int d = 0; d < DD; ++d) {
            double acc = meansw[d];
            for (int e = 0; e <= d; ++e)
                acc += Leff[d*DD + e] * (double)sh[e];
            comb[d] = acc;
        }
        PM0[h] = (float)(SCALE_F * (double)AB_F * comb[0]);
        PM1[h] = (float)(SCALE_F * (double)AB_F * comb[1]);
        N0[h]  = (float)comb[2];
        N1[h]  = (float)comb[3];
        #pragma unroll
        for (int i = 0; i < INPUT; ++i)
            IvL[h][i] = (float)(SCALE_F * 0.1 * comb[4 + i]);
    }
    __syncthreads();

    // ---- persistent per-role state ----
    v2f AM0[4], AM1[4], NM0[4], NM1[4], H[4];
    float sn0 = 0.0f, sn1 = 0.0f;
    f4v IvA[3], IvC[3];
    float zf = 0.0f, wst = 0.0f;
    const int pid = (wid - 1)*64 + lane;   // producer id 0..191
    const int zi  = lane - 56;

    if (wid == 0) {
        // consumer owns h = lane + 64*m; pair q = m>>1, pr = m&1
        #pragma unroll
        for (int q = 0; q < 4; ++q) {
            int ha = lane + 64*(2*q), hb = lane + 64*(2*q + 1);
            AM0[q] = (v2f){PM0[ha], PM0[hb]};
            AM1[q] = (v2f){PM1[ha], PM1[hb]};
            NM0[q] = (v2f){-2.0f*N0[ha], -2.0f*N0[hb]};
            NM1[q] = (v2f){-2.0f*N1[ha], -2.0f*N1[hb]};
            sn0 += N0[ha] + N0[hb];
            sn1 += N1[ha] + N1[hb];
            H[q]   = (v2f){0.0f, 0.0f};
        }
    } else {
        #pragma unroll
        for (int q = 0; q < 3; ++q) {
            int h = pid + 192*q;
            if (h < HIDDEN) {
                IvA[q] = *(const f4v*)&IvL[h][0];
                IvC[q] = *(const f4v*)&IvL[h][4];
            }
        }
    }

    // producer: fill IxP tile tg; wave1 lanes 56-63 emit the z-filter outputs
    auto produce = [&](int tg) {
        const int pb = tg & 1;
        const float* xs = xsB[pb];
        for (int tt = 0; tt < TTILE; ++tt) {
            f4v xa = *(const f4v*)&xs[tt*INPUT];
            f4v xc = *(const f4v*)&xs[tt*INPUT + 4];
            #pragma unroll
            for (int q = 0; q < 3; ++q) {
                int h = pid + 192*q;
                if (h < HIDDEN) {
                    float v =      IvA[q].x * xa.x;
                    v = fmaf(IvA[q].y, xa.y, v);
                    v = fmaf(IvA[q].z, xa.z, v);
                    v = fmaf(IvA[q].w, xa.w, v);
                    v = fmaf(IvC[q].x, xc.x, v);
                    v = fmaf(IvC[q].y, xc.y, v);
                    v = fmaf(IvC[q].z, xc.z, v);
                    v = fmaf(IvC[q].w, xc.w, v);
                    IxP[pb][tt][(h >> 7)][h & 63][(h >> 6) & 1] = v;
                }
            }
        }
        if (wid == 1 && lane >= 56) {
            #pragma unroll 4
            for (int tt = 0; tt < TTILE; ++tt) {
                zf = fmaf(0.9f, zf, 0.1f * xs[tt*INPUT + zi]);
                outb[(tg*TTILE + tt)*KOUT + 2 + zi] = zf;
            }
        }
    };

    // w-EMA for cols 0,1 (wave 1, lanes 54,55) — reads lane 0's v copy
    auto process_w = [&](int tile) {
        if (lane == 54 || lane == 55) {
            const int widx = lane & 1;
            for (int tt = 0; tt < TTILE; ++tt) {
                wst = fmaf(0.9f, wst, AB_F * vr2[tile & 1][tt][0][widx]);
                outb[(tile*TTILE + tt)*KOUT + widx] = wst;
            }
        }
    };

    if (wid != 0) produce(0);
    __syncthreads();

    for (int T = 0; T < NTILES; ++T) {
        if (wid == 0) {
            const int pb = T & 1;
            v2f CA[4], CB[4];
            #pragma unroll
            for (int q = 0; q < 4; ++q)
                CA[q] = *(const v2f*)&IxP[pb][0][q][lane][0];

            // one scan step on register set CUR, prefetching into NXT
            auto step = [&](int tt, v2f (&CUR)[4], v2f (&NXT)[4]) {
                if (tt < TTILE-1) {            // b64 prefetch, 2-way banks = free
                    #pragma unroll
                    for (int q = 0; q < 4; ++q)
                        NXT[q] = *(const v2f*)&IxP[pb][tt+1][q][lane][0];
                }
                // r = 1/(exp2(H)+1); dot folds tanh: p = sn + sum(-2n * r)
                v2f R[4];
                #pragma unroll
                for (int q = 0; q < 4; ++q) {
                    v2f E;
                    E.x = __builtin_amdgcn_exp2f(H[q].x);
                    E.y = __builtin_amdgcn_exp2f(H[q].y);
                    v2f A = E + 1.0f;
                    R[q].x = __builtin_amdgcn_rcpf(A.x);
                    R[q].y = __builtin_amdgcn_rcpf(A.y);
                }
                v2f s0 = R[0]*NM0[0];
                s0 = pk_fma(R[1], NM0[1], s0);
                s0 = pk_fma(R[2], NM0[2], s0);
                s0 = pk_fma(R[3], NM0[3], s0);
                v2f s1 = R[0]*NM1[0];
                s1 = pk_fma(R[1], NM1[1], s1);
                s1 = pk_fma(R[2], NM1[2], s1);
                s1 = pk_fma(R[3], NM1[3], s1);
                float p0 = (s0.x + s0.y) + sn0;
                float p1 = (s1.x + s1.y) + sn1;

                float v0 = wave_allsum(p0);
                float v1 = wave_allsum(p1);

                const v2f nine = {0.9f, 0.9f};
                v2f hc0 = pk_fma(nine, H[0], CUR[0]);  // fills DPP shadow
                v2f hc1 = pk_fma(nine, H[1], CUR[1]);
                v2f hc2 = pk_fma(nine, H[2], CUR[2]);
                v2f hc3 = pk_fma(nine, H[3], CUR[3]);

                v2f v0v = {v0, v0}, v1v = {v1, v1};
                H[0] = pk_fma(AM0[0], v0v, pk_fma(AM1[0], v1v, hc0));
                H[1] = pk_fma(AM0[1], v0v, pk_fma(AM1[1], v1v, hc1));
                H[2] = pk_fma(AM0[2], v0v, pk_fma(AM1[2], v1v, hc2));
                H[3] = pk_fma(AM0[3], v0v, pk_fma(AM1[3], v1v, hc3));

                // unconditional per-lane copy (identical values) — no exec games
                *(v2f*)&vr2[pb][tt][lane][0] = (v2f){v0, v1};
            };

            #pragma unroll
            for (int tp = 0; tp < TTILE; tp += 2) {   // explicit reg ping-pong
                step(tp,     CA, CB);
                step(tp + 1, CB, CA);
            }
        } else {
            if (T + 1 < NTILES) produce(T + 1);
            if (wid == 2 && T + 2 < NTILES) {
                const int base = (T + 2)*(TTILE*INPUT);
                xsB[T & 1][lane]      = xb[base + lane];
                xsB[T & 1][lane + 64] = xb[base + lane + 64];
            }
            if (wid == 1 && T >= 1) process_w(T - 1);
        }
        __syncthreads();
    }
    if (wid == 1) process_w(NTILES - 1);
}

extern "C" void kernel_launch(void* const* d_in, const int* in_sizes, int n_in,
                              void* d_out, int out_size, void* d_ws, size_t ws_size,
                              hipStream_t stream) {
    (void)d_ws; (void)ws_size;
    const float* x          = (const float*)d_in[0];
    const float* means      = (const float*)d_in[1];
    const float* scale_tril = (const float*)d_in[2];
    const float* mixw       = (const float*)d_in[3];
    const float* seeds      = (const float*)d_in[4];
    const int*   cur_seeds  = (const int*)d_in[5];
    float* out = (float*)d_out;

    fsm_rnn_kernel<<<BATCH, 256, 0, stream>>>(
        x, means, scale_tril, mixw, seeds, cur_seeds, out);
}

// Round 11
// 458.199 us; speedup vs baseline: 1.0131x; 1.0131x over previous
//
#include <hip/hip_runtime.h>
#include <math.h>

#define HIDDEN  512
#define INPUT   8
#define NUM_MIX 2
#define BATCH   64
#define SEQ     2048
#define DD      12
#define KOUT    10
#define TTILE   16
#define NTILES  (SEQ/TTILE)

// h-state kept pre-scaled by 2*log2(e): tanh(h) = 1 - 2*rcp(exp2(h_s)+1)
#define SCALE_F 2.8853900817779268
#define AB_F    0.09765625f   /* alpha*BASE_SCALE/HIDDEN = 50/512 */

typedef float v2f __attribute__((ext_vector_type(2)));
typedef float f4v __attribute__((ext_vector_type(4)));
typedef unsigned int v2u __attribute__((ext_vector_type(2)));

__device__ __forceinline__ v2f pk_fma(v2f a, v2f b, v2f c) {
    return __builtin_elementwise_fma(a, b, c);
}

template<int CTRL>
__device__ __forceinline__ float dpp_add(float x) {
    int y = __builtin_amdgcn_update_dpp(0, __float_as_int(x), CTRL, 0xF, 0xF, true);
    return x + __int_as_float(y);
}
__device__ __forceinline__ float wave_allsum(float x) {
    x = dpp_add<0x111>(x);   // row_shr:1
    x = dpp_add<0x112>(x);   // row_shr:2
    x = dpp_add<0x114>(x);   // row_shr:4
    x = dpp_add<0x118>(x);   // row_shr:8
    x = dpp_add<0x142>(x);   // row_bcast:15
    x = dpp_add<0x143>(x);   // row_bcast:31
    return __int_as_float(__builtin_amdgcn_readlane(__float_as_int(x), 63));
}

// Fused dual reduction: v0 = sum64(p0), v1 = sum64(p1).
// Uses gfx950 v_permlane32_swap_b32 to fold both sums into ONE 5-level DPP
// chain: after swap+add, lanes 0-31 hold p0 pair-sums, 32-63 hold p1's.
__device__ __forceinline__ void allsum2(float p0, float p1,
                                        float& v0, float& v1) {
#if __has_builtin(__builtin_amdgcn_permlane32_swap)
    v2u sw = __builtin_amdgcn_permlane32_swap(
        __float_as_uint(p0), __float_as_uint(p1), false, false);
    float z = __uint_as_float(sw.x) + __uint_as_float(sw.y);
    z = dpp_add<0x111>(z);   // row_shr:1
    z = dpp_add<0x112>(z);   // row_shr:2
    z = dpp_add<0x114>(z);   // row_shr:4
    z = dpp_add<0x118>(z);   // row_shr:8  -> lane15/31/47/63 = row sums
    z = dpp_add<0x142>(z);   // row_bcast:15 -> lane31 = S0, lane63 = S1
    v0 = __int_as_float(__builtin_amdgcn_readlane(__float_as_int(z), 31));
    v1 = __int_as_float(__builtin_amdgcn_readlane(__float_as_int(z), 63));
#else
    v0 = wave_allsum(p0);
    v1 = wave_allsum(p1);
#endif
}

__global__ __launch_bounds__(256) void fsm_rnn_kernel(
    const float* __restrict__ x,          // (B, SEQ, INPUT)
    const float* __restrict__ means,      // (NUM_MIX, DD)
    const float* __restrict__ scale_tril, // (NUM_MIX, DD, DD)
    const float* __restrict__ mixw,       // (NUM_MIX,)
    const float* __restrict__ seeds,      // (4, HIDDEN, DD)
    const int*   __restrict__ cur_seeds,  // (B,)
    float*       __restrict__ out)        // (B, SEQ, KOUT)
{
    // IxP pair-layout: [dbuf][tt][q][lane][pr] holds unit h = lane + 64*(2q+pr)
    __shared__ __align__(16) float IxP[2][TTILE][4][64][2];  // 64KB
    __shared__ __align__(16) float xsB[2][TTILE*INPUT];      // 1KB raw x tiles
    __shared__ __align__(16) float IvL[HIDDEN][INPUT];       // 16KB alpha*I (scaled)
    __shared__ float PM0[HIDDEN], PM1[HIDDEN], N0[HIDDEN], N1[HIDDEN]; // 8KB
    __shared__ __align__(8) float vr2[2][TTILE][64][2];      // 16KB per-lane v copies
    __shared__ double Leff[DD*DD];
    __shared__ double meansw[DD];

    const int tid  = threadIdx.x;
    const int lane = tid & 63;
    const int wid  = tid >> 6;
    const int b    = blockIdx.x;
    const int s    = cur_seeds[b];
    const float* xb = x + (size_t)b * SEQ * INPUT;
    float* outb = out + (size_t)b * SEQ * KOUT;

    // ---- mixture weights ----
    double w0 = fmax((double)mixw[0], 1e-6);
    double w1 = fmax((double)mixw[1], 1e-6);
    double wsum = w0 + w1; w0 /= wsum; w1 /= wsum;

    // ---- weighted clamped-tril L, weighted means ----
    if (tid < DD*DD) {
        int d = tid / DD, e = tid % DD;
        double acc = 0.0;
        #pragma unroll
        for (int i = 0; i < NUM_MIX; ++i) {
            float v = scale_tril[i*DD*DD + d*DD + e];
            float c = (d > e) ? v : (d == e ? fabsf(v - 1e-12f) + 1e-12f : 0.0f);
            acc += (i == 0 ? w0 : w1) * (double)c;
        }
        Leff[tid] = acc;
    }
    if (tid < DD)
        meansw[tid] = w0 * (double)means[tid] + w1 * (double)means[DD + tid];
    if (tid < 2*TTILE*INPUT)
        ((float*)xsB)[tid] = xb[tid];          // stage x tiles 0,1
    __syncthreads();

    // ---- per-h params (double), stored pre-scaled ----
    #pragma unroll
    for (int rr = 0; rr < 2; ++rr) {
        int h = tid + rr*256;
        const float* sh = &seeds[(s*HIDDEN + h)*DD];
        double comb[DD];
        #pragma unroll
        for (int d = 0; d < DD; ++d) {
            double acc = meansw[d];
            for (int e = 0; e <= d; ++e)
                acc += Leff[d*DD + e] * (double)sh[e];
            comb[d] = acc;
        }
        PM0[h] = (float)(SCALE_F * (double)AB_F * comb[0]);
        PM1[h] = (float)(SCALE_F * (double)AB_F * comb[1]);
        N0[h]  = (float)comb[2];
        N1[h]  = (float)comb[3];
        #pragma unroll
        for (int i = 0; i < INPUT; ++i)
            IvL[h][i] = (float)(SCALE_F * 0.1 * comb[4 + i]);
    }
    __syncthreads();

    // ---- persistent per-role state ----
    v2f AM0[4], AM1[4], NN0v[4], NN1v[4], H[4];
    f4v IvA[3], IvC[3];
    float zf = 0.0f, wst = 0.0f;
    const int pid = (wid - 1)*64 + lane;   // producer id 0..191
    const int zi  = lane - 56;

    if (wid == 0) {
        // consumer owns h = lane + 64*m; pair q = m>>1, pr = m&1
        #pragma unroll
        for (int q = 0; q < 4; ++q) {
            int ha = lane + 64*(2*q), hb = lane + 64*(2*q + 1);
            AM0[q]  = (v2f){PM0[ha], PM0[hb]};
            AM1[q]  = (v2f){PM1[ha], PM1[hb]};
            NN0v[q] = (v2f){N0[ha],  N0[hb]};
            NN1v[q] = (v2f){N1[ha],  N1[hb]};
            H[q]    = (v2f){0.0f, 0.0f};
        }
    } else {
        #pragma unroll
        for (int q = 0; q < 3; ++q) {
            int h = pid + 192*q;
            if (h < HIDDEN) {
                IvA[q] = *(const f4v*)&IvL[h][0];
                IvC[q] = *(const f4v*)&IvL[h][4];
            }
        }
    }

    // producer: fill IxP tile tg; wave1 lanes 56-63 emit the z-filter outputs
    auto produce = [&](int tg) {
        const int pb = tg & 1;
        const float* xs = xsB[pb];
        for (int tt = 0; tt < TTILE; ++tt) {
            f4v xa = *(const f4v*)&xs[tt*INPUT];
            f4v xc = *(const f4v*)&xs[tt*INPUT + 4];
            #pragma unroll
            for (int q = 0; q < 3; ++q) {
                int h = pid + 192*q;
                if (h < HIDDEN) {
                    float v =      IvA[q].x * xa.x;
                    v = fmaf(IvA[q].y, xa.y, v);
                    v = fmaf(IvA[q].z, xa.z, v);
                    v = fmaf(IvA[q].w, xa.w, v);
                    v = fmaf(IvC[q].x, xc.x, v);
                    v = fmaf(IvC[q].y, xc.y, v);
                    v = fmaf(IvC[q].z, xc.z, v);
                    v = fmaf(IvC[q].w, xc.w, v);
                    IxP[pb][tt][(h >> 7)][h & 63][(h >> 6) & 1] = v;
                }
            }
        }
        if (wid == 1 && lane >= 56) {
            #pragma unroll 4
            for (int tt = 0; tt < TTILE; ++tt) {
                zf = fmaf(0.9f, zf, 0.1f * xs[tt*INPUT + zi]);
                outb[(tg*TTILE + tt)*KOUT + 2 + zi] = zf;
            }
        }
    };

    // w-EMA for cols 0,1 (wave 1, lanes 54,55) — reads lane 0's v copy
    auto process_w = [&](int tile) {
        if (lane == 54 || lane == 55) {
            const int widx = lane & 1;
            for (int tt = 0; tt < TTILE; ++tt) {
                wst = fmaf(0.9f, wst, AB_F * vr2[tile & 1][tt][0][widx]);
                outb[(tile*TTILE + tt)*KOUT + widx] = wst;
            }
        }
    };

    if (wid != 0) produce(0);
    __syncthreads();

    for (int T = 0; T < NTILES; ++T) {
        if (wid == 0) {
            const int pb = T & 1;
            v2f CC[4], CN[4];
            #pragma unroll
            for (int q = 0; q < 4; ++q)
                CC[q] = *(const v2f*)&IxP[pb][0][q][lane][0];
            #pragma unroll
            for (int tt = 0; tt < TTILE; ++tt) {
                if (tt < TTILE-1) {            // b64 prefetch, 2-way banks = free
                    #pragma unroll
                    for (int q = 0; q < 4; ++q)
                        CN[q] = *(const v2f*)&IxP[pb][tt+1][q][lane][0];
                }
                // tanh: scalar transcendentals, packed arithmetic (R4 numerics)
                v2f TH[4];
                #pragma unroll
                for (int q = 0; q < 4; ++q) {
                    v2f E;
                    E.x = __builtin_amdgcn_exp2f(H[q].x);
                    E.y = __builtin_amdgcn_exp2f(H[q].y);
                    v2f A = E + 1.0f;
                    v2f R;
                    R.x = __builtin_amdgcn_rcpf(A.x);
                    R.y = __builtin_amdgcn_rcpf(A.y);
                    const v2f m2 = {-2.0f, -2.0f}, one = {1.0f, 1.0f};
                    TH[q] = pk_fma(m2, R, one);
                }
                v2f s0 = TH[0]*NN0v[0];
                s0 = pk_fma(TH[1], NN0v[1], s0);
                s0 = pk_fma(TH[2], NN0v[2], s0);
                s0 = pk_fma(TH[3], NN0v[3], s0);
                v2f s1 = TH[0]*NN1v[0];
                s1 = pk_fma(TH[1], NN1v[1], s1);
                s1 = pk_fma(TH[2], NN1v[2], s1);
                s1 = pk_fma(TH[3], NN1v[3], s1);
                float p0 = s0.x + s0.y;
                float p1 = s1.x + s1.y;

                float v0, v1;
                allsum2(p0, p1, v0, v1);   // fused dual reduction (permlane32)

                const v2f nine = {0.9f, 0.9f};
                v2f hc0 = pk_fma(nine, H[0], CC[0]);  // fills DPP shadow
                v2f hc1 = pk_fma(nine, H[1], CC[1]);
                v2f hc2 = pk_fma(nine, H[2], CC[2]);
                v2f hc3 = pk_fma(nine, H[3], CC[3]);

                v2f v0v = {v0, v0}, v1v = {v1, v1};
                H[0] = pk_fma(AM0[0], v0v, pk_fma(AM1[0], v1v, hc0));
                H[1] = pk_fma(AM0[1], v0v, pk_fma(AM1[1], v1v, hc1));
                H[2] = pk_fma(AM0[2], v0v, pk_fma(AM1[2], v1v, hc2));
                H[3] = pk_fma(AM0[3], v0v, pk_fma(AM1[3], v1v, hc3));

                // unconditional per-lane copy (identical values) — no exec games
                *(v2f*)&vr2[pb][tt][lane][0] = (v2f){v0, v1};

                #pragma unroll
                for (int q = 0; q < 4; ++q) CC[q] = CN[q];
            }
        } else {
            if (T + 1 < NTILES) produce(T + 1);
            if (wid == 2 && T + 2 < NTILES) {
                const int base = (T + 2)*(TTILE*INPUT);
                xsB[T & 1][lane]      = xb[base + lane];
                xsB[T & 1][lane + 64] = xb[base + lane + 64];
            }
            if (wid == 1 && T >= 1) process_w(T - 1);
        }
        __syncthreads();
    }
    if (wid == 1) process_w(NTILES - 1);
}

extern "C" void kernel_launch(void* const* d_in, const int* in_sizes, int n_in,
                              void* d_out, int out_size, void* d_ws, size_t ws_size,
                              hipStream_t stream) {
    (void)d_ws; (void)ws_size;
    const float* x          = (const float*)d_in[0];
    const float* means      = (const float*)d_in[1];
    const float* scale_tril = (const float*)d_in[2];
    const float* mixw       = (const float*)d_in[3];
    const float* seeds      = (const float*)d_in[4];
    const int*   cur_seeds  = (const int*)d_in[5];
    float* out = (float*)d_out;

    fsm_rnn_kernel<<<BATCH, 256, 0, stream>>>(
        x, means, scale_tril, mixw, seeds, cur_seeds, out);
}